// Round 6
// baseline (2342.889 us; speedup 1.0000x reference)
//
#include <hip/hip_runtime.h>

// Decoder: T=32-step attention LSTM, BATCH=LATENT=HIDDEN=1024.
// R6 = R3 (best: 1640us) + two epilogue folds:
//   gemm1 chunk-0 folds z_lat (f32) -> lstm reads only 2 bf16 partials
//   gemm2 chunk-0 folds s_lat (f32) -> attn reads only 8 bf16 partials
// GEMM core unchanged from R3: 128x128 tile, BK=64 double-buffered (64KB LDS),
// T2 both-sides XOR swizzle, global_load_lds width=16.

#define T_ 32

typedef __attribute__((ext_vector_type(8))) short short8;
typedef __attribute__((ext_vector_type(4))) float f32x4;

__device__ __forceinline__ unsigned short bf16u(float x) {
  unsigned int u = __float_as_uint(x);
  u += 0x7FFFu + ((u >> 16) & 1u);
  return (unsigned short)(u >> 16);
}
__device__ __forceinline__ float b2f(unsigned short u) {
  return __uint_as_float(((unsigned int)u) << 16);
}
__device__ __forceinline__ ushort4 pack4(float a, float b, float c, float d) {
  ushort4 v; v.x = bf16u(a); v.y = bf16u(b); v.z = bf16u(c); v.w = bf16u(d); return v;
}
__device__ __forceinline__ float sigmoidf_(float x) { return 1.f / (1.f + __expf(-x)); }
__device__ __forceinline__ float tanhf_(float x) { return 1.f - 2.f / (__expf(2.f * x) + 1.f); }

// ---------- transpose f32 [srcK][srcN] -> bf16 dst[n][dstStride] at col offset ----------
__global__ void k_transpose(const float* __restrict__ src, int srcN,
                            unsigned short* __restrict__ dst, int dstStride, int dstColOff) {
  __shared__ float tile[32][33];
  int n0 = blockIdx.x * 32, k0 = blockIdx.y * 32;
  int tx = threadIdx.x, ty = threadIdx.y;
#pragma unroll
  for (int i = 0; i < 4; ++i)
    tile[ty + i * 8][tx] = src[(size_t)(k0 + ty + i * 8) * srcN + n0 + tx];
  __syncthreads();
#pragma unroll
  for (int i = 0; i < 4; ++i)
    dst[(size_t)(n0 + ty + i * 8) * dstStride + dstColOff + k0 + tx] = bf16u(tile[tx][ty + i * 8]);
}

// ---------- one-time init ----------
__global__ __launch_bounds__(256) void k_init(const float* __restrict__ h0,
                                              const float* __restrict__ c0,
                                              const float* __restrict__ latent,
                                              unsigned short* __restrict__ A1,
                                              unsigned short* __restrict__ A2,
                                              unsigned short* __restrict__ latbf,
                                              float* __restrict__ c_st) {
  int r = blockIdx.x; int j = threadIdx.x * 4;
  const float4 hv = *(const float4*)&h0[(size_t)r * 1024 + j];
  const float4 cv = *(const float4*)&c0[(size_t)r * 1024 + j];
  const float4 lv = *(const float4*)&latent[(size_t)r * 1024 + j];
  *(ushort4*)&A2[(size_t)r * 2048 + j]        = pack4(hv.x, hv.y, hv.z, hv.w);
  *(ushort4*)&A2[(size_t)r * 2048 + 1024 + j] = pack4(cv.x, cv.y, cv.z, cv.w);
  *(ushort4*)&A1[(size_t)r * 2048 + 1024 + j] = pack4(hv.x, hv.y, hv.z, hv.w);
  *(ushort4*)&latbf[(size_t)r * 1024 + j]     = pack4(lv.x, lv.y, lv.z, lv.w);
  *(float4*)&c_st[(size_t)r * 1024 + j] = cv;
}

__global__ void k_bias(const float* __restrict__ b1, const float* __restrict__ b2,
                       float* __restrict__ bias_s) {
  int i = blockIdx.x * 256 + threadIdx.x;
  bias_s[i] = b1[i] + b2[i];
}

// ---------- MFMA GEMM (split-K, 2-phase dbuf BK=64, T2 both-sides swizzle) ----------
// Cf!=null: f32 out + bias[col] (setup, gridDim.z==1).
// Else: bf16 partial at Cb[z][1024][N]; blockIdx.z==0 && addf: fold f32 addf in.
__global__ __launch_bounds__(256) void k_gemm(const unsigned short* __restrict__ A, int lda,
                                              const unsigned short* __restrict__ Bt, int ldb,
                                              int Kchunk,
                                              const float* __restrict__ bias,
                                              float* __restrict__ Cf,
                                              unsigned short* __restrict__ Cb,
                                              const float* __restrict__ addf, int N) {
  __shared__ unsigned short Al[2][128 * 64];
  __shared__ unsigned short Bl[2][128 * 64];
  const int tid = threadIdx.x;
  const int w = tid >> 6, l = tid & 63;
  const int row0 = blockIdx.y * 128, col0 = blockIdx.x * 128;
  const int wr = (w >> 1) * 64, wc = (w & 1) * 64;
  const int lr = l & 15;
  const int srow = (l >> 3);                       // 0..7 within chunk
  const int scol_src = ((l & 7) ^ srow) * 8;       // swizzled global column (elements)
  const int kbeg = blockIdx.z * Kchunk;
  const int nsteps = Kchunk >> 6;

  f32x4 acc[4][4] = {};

  auto stage = [&](int buf, int k0) {
#pragma unroll
    for (int it = 0; it < 4; ++it) {
      int chunk = w * 4 + it;           // wave-uniform
      int r = chunk * 8 + srow;
      const unsigned short* ga = A + (size_t)(row0 + r) * lda + k0 + scol_src;
      const unsigned short* gb = Bt + (size_t)(col0 + r) * ldb + k0 + scol_src;
      __builtin_amdgcn_global_load_lds(
          (const __attribute__((address_space(1))) unsigned int*)ga,
          (__attribute__((address_space(3))) unsigned int*)((char*)&Al[buf][0] + chunk * 1024), 16, 0, 0);
      __builtin_amdgcn_global_load_lds(
          (const __attribute__((address_space(1))) unsigned int*)gb,
          (__attribute__((address_space(3))) unsigned int*)((char*)&Bl[buf][0] + chunk * 1024), 16, 0, 0);
    }
  };

  stage(0, kbeg);
  __syncthreads();
  int cur = 0;
  for (int s = 0; s < nsteps; ++s) {
    if (s + 1 < nsteps) stage(cur ^ 1, kbeg + (s + 1) * 64);  // prefetch next tile
#pragma unroll
    for (int kk = 0; kk < 2; ++kk) {
      const int c2 = kk * 64 + (l >> 4) * 16;     // byte col within 128B row
      short8 a[4], b[4];
#pragma unroll
      for (int m = 0; m < 4; ++m) {
        int r = wr + m * 16 + lr;
        a[m] = *(const short8*)((char*)&Al[cur][0] + r * 128 + (c2 ^ ((r & 7) << 4)));
      }
#pragma unroll
      for (int n = 0; n < 4; ++n) {
        int r = wc + n * 16 + lr;
        b[n] = *(const short8*)((char*)&Bl[cur][0] + r * 128 + (c2 ^ ((r & 7) << 4)));
      }
#pragma unroll
      for (int m = 0; m < 4; ++m)
#pragma unroll
        for (int n = 0; n < 4; ++n)
          acc[m][n] = __builtin_amdgcn_mfma_f32_16x16x32_bf16(a[m], b[n], acc[m][n], 0, 0, 0);
    }
    __syncthreads();
    cur ^= 1;
  }

  const int rbase = (l >> 4) * 4;
  if (Cf) {
#pragma unroll
    for (int m = 0; m < 4; ++m)
#pragma unroll
      for (int rg = 0; rg < 4; ++rg) {
        int row = row0 + wr + m * 16 + rbase + rg;
#pragma unroll
        for (int n = 0; n < 4; ++n) {
          int col = col0 + wc + n * 16 + lr;
          Cf[(size_t)row * N + col] = acc[m][n][rg] + bias[col];
        }
      }
  } else {
    unsigned short* Cp = Cb + (size_t)blockIdx.z * (size_t)(gridDim.y * 128) * N;
    const int fold = (blockIdx.z == 0) && (addf != nullptr);
#pragma unroll
    for (int m = 0; m < 4; ++m)
#pragma unroll
      for (int rg = 0; rg < 4; ++rg) {
        int row = row0 + wr + m * 16 + rbase + rg;
#pragma unroll
        for (int n = 0; n < 4; ++n) {
          int col = col0 + wc + n * 16 + lr;
          float v = acc[m][n][rg];
          if (fold) v += addf[(size_t)row * N + col];
          Cp[(size_t)row * N + col] = bf16u(v);
        }
      }
  }
}

// ---------- LSTM elementwise: z = p0 + p1 (bf16 partials; z_lat pre-folded in p0) ----------
__global__ __launch_bounds__(256) void k_lstm(const unsigned short* __restrict__ zp,
                                              float* __restrict__ c_st,
                                              unsigned short* __restrict__ A1,
                                              unsigned short* __restrict__ A2,
                                              const float* __restrict__ Wmu,
                                              const float* __restrict__ bmu,
                                              float* __restrict__ out, int t) {
  __shared__ float red[4];
  const size_t Z1 = (size_t)1024 * 4096;
  int r = blockIdx.x; int tid = threadIdx.x; int j = tid * 4;
  float g4[4][4];
#pragma unroll
  for (int g = 0; g < 4; ++g) {
    const ushort4 p0 = *(const ushort4*)&zp[(size_t)r * 4096 + g * 1024 + j];
    const ushort4 p1 = *(const ushort4*)&zp[Z1 + (size_t)r * 4096 + g * 1024 + j];
    g4[g][0] = b2f(p0.x) + b2f(p1.x);
    g4[g][1] = b2f(p0.y) + b2f(p1.y);
    g4[g][2] = b2f(p0.z) + b2f(p1.z);
    g4[g][3] = b2f(p0.w) + b2f(p1.w);
  }
  const float4 cv = *(const float4*)&c_st[(size_t)r * 1024 + j];
  const float4 wm = *(const float4*)&Wmu[j];
  float cc[4] = {cv.x, cv.y, cv.z, cv.w}, wv[4] = {wm.x, wm.y, wm.z, wm.w};
  float cn[4], hn[4];
  float part = 0.f;
#pragma unroll
  for (int q = 0; q < 4; ++q) {
    float c2 = sigmoidf_(g4[1][q]) * cc[q] + sigmoidf_(g4[0][q]) * tanhf_(g4[2][q]);
    float h2 = sigmoidf_(g4[3][q]) * tanhf_(c2);
    cn[q] = c2; hn[q] = h2; part += h2 * wv[q];
  }
  *(float4*)&c_st[(size_t)r * 1024 + j] = make_float4(cn[0], cn[1], cn[2], cn[3]);
  *(ushort4*)&A2[(size_t)r * 2048 + j]        = pack4(hn[0], hn[1], hn[2], hn[3]);
  *(ushort4*)&A2[(size_t)r * 2048 + 1024 + j] = pack4(cn[0], cn[1], cn[2], cn[3]);
  *(ushort4*)&A1[(size_t)r * 2048 + 1024 + j] = pack4(hn[0], hn[1], hn[2], hn[3]);
#pragma unroll
  for (int off = 32; off > 0; off >>= 1) part += __shfl_down(part, off, 64);
  if ((tid & 63) == 0) red[tid >> 6] = part;
  __syncthreads();
  if (tid == 0) out[(size_t)r * T_ + t] = red[0] + red[1] + red[2] + red[3] + bmu[0];
}

// ---------- attention: spre = sum8 partials (s_lat pre-folded) -> tanh -> softmax -> ctx ----------
__global__ __launch_bounds__(256) void k_attn(const unsigned short* __restrict__ sp8,
                                              const float* __restrict__ latent,
                                              unsigned short* __restrict__ A1) {
  __shared__ float red[4];
  const size_t P = (size_t)1024 * 1024;
  int r = blockIdx.x; int tid = threadIdx.x; int j = tid * 4;
  float sv[4] = {0.f, 0.f, 0.f, 0.f};
#pragma unroll
  for (int sidx = 0; sidx < 8; ++sidx) {
    const ushort4 q = *(const ushort4*)&sp8[sidx * P + (size_t)r * 1024 + j];
    sv[0] += b2f(q.x); sv[1] += b2f(q.y); sv[2] += b2f(q.z); sv[3] += b2f(q.w);
  }
  float s[4] = {tanhf_(sv[0]), tanhf_(sv[1]), tanhf_(sv[2]), tanhf_(sv[3])};
  float mx = fmaxf(fmaxf(s[0], s[1]), fmaxf(s[2], s[3]));
#pragma unroll
  for (int off = 32; off > 0; off >>= 1) mx = fmaxf(mx, __shfl_xor(mx, off, 64));
  if ((tid & 63) == 0) red[tid >> 6] = mx;
  __syncthreads();
  mx = fmaxf(fmaxf(red[0], red[1]), fmaxf(red[2], red[3]));
  __syncthreads();
  float e[4], ps = 0.f;
#pragma unroll
  for (int q = 0; q < 4; ++q) { e[q] = __expf(s[q] - mx); ps += e[q]; }
#pragma unroll
  for (int off = 32; off > 0; off >>= 1) ps += __shfl_xor(ps, off, 64);
  if ((tid & 63) == 0) red[tid >> 6] = ps;
  __syncthreads();
  float inv = 1.f / (red[0] + red[1] + red[2] + red[3]);
  const float4 lv = *(const float4*)&latent[(size_t)r * 1024 + j];
  *(ushort4*)&A1[(size_t)r * 2048 + j] =
      pack4(e[0] * inv * lv.x, e[1] * inv * lv.y, e[2] * inv * lv.z, e[3] * inv * lv.w);
}

extern "C" void kernel_launch(void* const* d_in, const int* in_sizes, int n_in,
                              void* d_out, int out_size, void* d_ws, size_t ws_size,
                              hipStream_t stream) {
  const float* latent = (const float*)d_in[0];
  const float* h0  = (const float*)d_in[1];
  const float* c0  = (const float*)d_in[2];
  const float* Wk  = (const float*)d_in[3];
  const float* Wr  = (const float*)d_in[4];
  const float* b   = (const float*)d_in[5];
  const float* W1  = (const float*)d_in[6];
  const float* b1  = (const float*)d_in[7];
  const float* W2  = (const float*)d_in[8];
  const float* b2  = (const float*)d_in[9];
  const float* Wmu = (const float*)d_in[10];
  const float* bmu = (const float*)d_in[11];
  float* out = (float*)d_out;

  char* p = (char*)d_ws;
  auto alloc = [&](size_t bytes) { void* r = (void*)p; p += (bytes + 255) & ~(size_t)255; return r; };
  unsigned short* Wzh_t = (unsigned short*)alloc((size_t)4096 * 2048 * 2);  // [n][k] k<1024:Wk_bot, else Wr
  unsigned short* Wk1_t = (unsigned short*)alloc((size_t)4096 * 1024 * 2);  // Wk_top^T
  unsigned short* W1t   = (unsigned short*)alloc((size_t)1024 * 1024 * 2);
  unsigned short* W2t   = (unsigned short*)alloc((size_t)1024 * 2048 * 2);
  unsigned short* latbf = (unsigned short*)alloc((size_t)1024 * 1024 * 2);
  unsigned short* A1    = (unsigned short*)alloc((size_t)1024 * 2048 * 2);  // [ctx | h] bf16
  unsigned short* A2    = (unsigned short*)alloc((size_t)1024 * 2048 * 2);  // [h | c] bf16
  float* z_lat  = (float*)alloc((size_t)1024 * 4096 * 4);
  float* s_lat  = (float*)alloc((size_t)1024 * 1024 * 4);
  unsigned short* z_part = (unsigned short*)alloc((size_t)2 * 1024 * 4096 * 2);
  unsigned short* spre_p = (unsigned short*)alloc((size_t)8 * 1024 * 1024 * 2);
  float* c_st   = (float*)alloc((size_t)1024 * 1024 * 4);
  float* bias_s = (float*)alloc((size_t)1024 * 4);

  dim3 tb(32, 8);
  k_transpose<<<dim3(128, 32), tb, 0, stream>>>(Wk, 4096, Wk1_t, 1024, 0);
  k_transpose<<<dim3(128, 32), tb, 0, stream>>>(Wk + (size_t)1024 * 4096, 4096, Wzh_t, 2048, 0);
  k_transpose<<<dim3(128, 32), tb, 0, stream>>>(Wr, 4096, Wzh_t, 2048, 1024);
  k_transpose<<<dim3(32, 64), tb, 0, stream>>>(W2, 1024, W2t, 2048, 0);
  k_transpose<<<dim3(32, 32), tb, 0, stream>>>(W1, 1024, W1t, 1024, 0);

  k_init<<<1024, 256, 0, stream>>>(h0, c0, latent, A1, A2, latbf, c_st);
  k_bias<<<4, 256, 0, stream>>>(b1, b2, bias_s);

  // setup GEMMs (f32 + bias): z_lat = latent@Wk_top + b ; s_lat = latent@W1 + (b1+b2)
  k_gemm<<<dim3(32, 8, 1), 256, 0, stream>>>(latbf, 1024, Wk1_t, 1024, 1024, b, z_lat, nullptr, nullptr, 4096);
  k_gemm<<<dim3(8, 8, 1), 256, 0, stream>>>(latbf, 1024, W1t, 1024, 1024, bias_s, s_lat, nullptr, nullptr, 1024);

  // initial attention partials from (h0, c0); chunk0 folds s_lat
  k_gemm<<<dim3(8, 8, 8), 256, 0, stream>>>(A2, 2048, W2t, 2048, 256, nullptr, nullptr, spre_p, s_lat, 1024);
  k_attn<<<1024, 256, 0, stream>>>(spre_p, latent, A1);

  for (int t = 0; t < T_; ++t) {
    // z partials = [ctx|h]@Wzh (splitK2); chunk0 folds z_lat
    k_gemm<<<dim3(32, 8, 2), 256, 0, stream>>>(A1, 2048, Wzh_t, 2048, 1024, nullptr, nullptr, z_part, z_lat, 4096);
    k_lstm<<<1024, 256, 0, stream>>>(z_part, c_st, A1, A2, Wmu, bmu, out, t);
    if (t < T_ - 1) {
      k_gemm<<<dim3(8, 8, 8), 256, 0, stream>>>(A2, 2048, W2t, 2048, 256, nullptr, nullptr, spre_p, s_lat, 1024);
      k_attn<<<1024, 256, 0, stream>>>(spre_p, latent, A1);
    }
  }
}

// Round 7
// 2317.839 us; speedup vs baseline: 1.0108x; 1.0108x over previous
//
#include <hip/hip_runtime.h>

// Decoder: T=32-step attention LSTM, BATCH=LATENT=HIDDEN=1024.
// R7 = R6 with ONE change: counted-vmcnt software pipeline in k_gemm.
//   Per K-step: issue stage(s+1) -> s_waitcnt vmcnt(8) (stage s landed, s+1 in
//   flight) -> s_barrier -> compute(s) -> s_barrier. No vmcnt(0) drain in loop.
//   (T4: loads stay in flight across barriers; fixes the latency convoy where
//   __syncthreads drained the prefetch every step: 3260cy/step vs 500cy compute.)

#define T_ 32

typedef __attribute__((ext_vector_type(8))) short short8;
typedef __attribute__((ext_vector_type(4))) float f32x4;

__device__ __forceinline__ unsigned short bf16u(float x) {
  unsigned int u = __float_as_uint(x);
  u += 0x7FFFu + ((u >> 16) & 1u);
  return (unsigned short)(u >> 16);
}
__device__ __forceinline__ float b2f(unsigned short u) {
  return __uint_as_float(((unsigned int)u) << 16);
}
__device__ __forceinline__ ushort4 pack4(float a, float b, float c, float d) {
  ushort4 v; v.x = bf16u(a); v.y = bf16u(b); v.z = bf16u(c); v.w = bf16u(d); return v;
}
__device__ __forceinline__ float sigmoidf_(float x) { return 1.f / (1.f + __expf(-x)); }
__device__ __forceinline__ float tanhf_(float x) { return 1.f - 2.f / (__expf(2.f * x) + 1.f); }

// ---------- transpose f32 [srcK][srcN] -> bf16 dst[n][dstStride] at col offset ----------
__global__ void k_transpose(const float* __restrict__ src, int srcN,
                            unsigned short* __restrict__ dst, int dstStride, int dstColOff) {
  __shared__ float tile[32][33];
  int n0 = blockIdx.x * 32, k0 = blockIdx.y * 32;
  int tx = threadIdx.x, ty = threadIdx.y;
#pragma unroll
  for (int i = 0; i < 4; ++i)
    tile[ty + i * 8][tx] = src[(size_t)(k0 + ty + i * 8) * srcN + n0 + tx];
  __syncthreads();
#pragma unroll
  for (int i = 0; i < 4; ++i)
    dst[(size_t)(n0 + ty + i * 8) * dstStride + dstColOff + k0 + tx] = bf16u(tile[tx][ty + i * 8]);
}

// ---------- one-time init ----------
__global__ __launch_bounds__(256) void k_init(const float* __restrict__ h0,
                                              const float* __restrict__ c0,
                                              const float* __restrict__ latent,
                                              unsigned short* __restrict__ A1,
                                              unsigned short* __restrict__ A2,
                                              unsigned short* __restrict__ latbf,
                                              float* __restrict__ c_st) {
  int r = blockIdx.x; int j = threadIdx.x * 4;
  const float4 hv = *(const float4*)&h0[(size_t)r * 1024 + j];
  const float4 cv = *(const float4*)&c0[(size_t)r * 1024 + j];
  const float4 lv = *(const float4*)&latent[(size_t)r * 1024 + j];
  *(ushort4*)&A2[(size_t)r * 2048 + j]        = pack4(hv.x, hv.y, hv.z, hv.w);
  *(ushort4*)&A2[(size_t)r * 2048 + 1024 + j] = pack4(cv.x, cv.y, cv.z, cv.w);
  *(ushort4*)&A1[(size_t)r * 2048 + 1024 + j] = pack4(hv.x, hv.y, hv.z, hv.w);
  *(ushort4*)&latbf[(size_t)r * 1024 + j]     = pack4(lv.x, lv.y, lv.z, lv.w);
  *(float4*)&c_st[(size_t)r * 1024 + j] = cv;
}

__global__ void k_bias(const float* __restrict__ b1, const float* __restrict__ b2,
                       float* __restrict__ bias_s) {
  int i = blockIdx.x * 256 + threadIdx.x;
  bias_s[i] = b1[i] + b2[i];
}

// ---------- MFMA GEMM (split-K, dbuf BK=64, T2 swizzle, counted-vmcnt pipeline) ----------
// Cf!=null: f32 out + bias[col] (setup, gridDim.z==1).
// Else: bf16 partial at Cb[z][1024][N]; blockIdx.z==0 && addf: fold f32 addf in.
__global__ __launch_bounds__(256) void k_gemm(const unsigned short* __restrict__ A, int lda,
                                              const unsigned short* __restrict__ Bt, int ldb,
                                              int Kchunk,
                                              const float* __restrict__ bias,
                                              float* __restrict__ Cf,
                                              unsigned short* __restrict__ Cb,
                                              const float* __restrict__ addf, int N) {
  __shared__ unsigned short Al[2][128 * 64];
  __shared__ unsigned short Bl[2][128 * 64];
  const int tid = threadIdx.x;
  const int w = tid >> 6, l = tid & 63;
  const int row0 = blockIdx.y * 128, col0 = blockIdx.x * 128;
  const int wr = (w >> 1) * 64, wc = (w & 1) * 64;
  const int lr = l & 15;
  const int srow = (l >> 3);                       // 0..7 within chunk
  const int scol_src = ((l & 7) ^ srow) * 8;       // swizzled global column (elements)
  const int kbeg = blockIdx.z * Kchunk;
  const int nsteps = Kchunk >> 6;

  f32x4 acc[4][4] = {};

  auto stage = [&](int buf, int k0) {
#pragma unroll
    for (int it = 0; it < 4; ++it) {
      int chunk = w * 4 + it;           // wave-uniform
      int r = chunk * 8 + srow;
      const unsigned short* ga = A + (size_t)(row0 + r) * lda + k0 + scol_src;
      const unsigned short* gb = Bt + (size_t)(col0 + r) * ldb + k0 + scol_src;
      __builtin_amdgcn_global_load_lds(
          (const __attribute__((address_space(1))) unsigned int*)ga,
          (__attribute__((address_space(3))) unsigned int*)((char*)&Al[buf][0] + chunk * 1024), 16, 0, 0);
      __builtin_amdgcn_global_load_lds(
          (const __attribute__((address_space(1))) unsigned int*)gb,
          (__attribute__((address_space(3))) unsigned int*)((char*)&Bl[buf][0] + chunk * 1024), 16, 0, 0);
    }
  };

  stage(0, kbeg);
  int cur = 0;
  for (int s = 0; s < nsteps; ++s) {
    if (s + 1 < nsteps) {
      stage(cur ^ 1, kbeg + (s + 1) * 64);  // prefetch next tile (8 loads, stays in flight)
      asm volatile("s_waitcnt vmcnt(8)" ::: "memory");   // own stage(s) landed
    } else {
      asm volatile("s_waitcnt vmcnt(0)" ::: "memory");   // last tile: full drain
    }
    __builtin_amdgcn_sched_barrier(0);
    __builtin_amdgcn_s_barrier();       // all waves' stage(s) landed -> safe to ds_read
#pragma unroll
    for (int kk = 0; kk < 2; ++kk) {
      const int c2 = kk * 64 + (l >> 4) * 16;     // byte col within 128B row
      short8 a[4], b[4];
#pragma unroll
      for (int m = 0; m < 4; ++m) {
        int r = wr + m * 16 + lr;
        a[m] = *(const short8*)((char*)&Al[cur][0] + r * 128 + (c2 ^ ((r & 7) << 4)));
      }
#pragma unroll
      for (int n = 0; n < 4; ++n) {
        int r = wc + n * 16 + lr;
        b[n] = *(const short8*)((char*)&Bl[cur][0] + r * 128 + (c2 ^ ((r & 7) << 4)));
      }
#pragma unroll
      for (int m = 0; m < 4; ++m)
#pragma unroll
        for (int n = 0; n < 4; ++n)
          acc[m][n] = __builtin_amdgcn_mfma_f32_16x16x32_bf16(a[m], b[n], acc[m][n], 0, 0, 0);
    }
    __builtin_amdgcn_s_barrier();       // all waves done reading buf[cur]; next stage may overwrite
    cur ^= 1;
  }

  const int rbase = (l >> 4) * 4;
  if (Cf) {
#pragma unroll
    for (int m = 0; m < 4; ++m)
#pragma unroll
      for (int rg = 0; rg < 4; ++rg) {
        int row = row0 + wr + m * 16 + rbase + rg;
#pragma unroll
        for (int n = 0; n < 4; ++n) {
          int col = col0 + wc + n * 16 + lr;
          Cf[(size_t)row * N + col] = acc[m][n][rg] + bias[col];
        }
      }
  } else {
    unsigned short* Cp = Cb + (size_t)blockIdx.z * (size_t)(gridDim.y * 128) * N;
    const int fold = (blockIdx.z == 0) && (addf != nullptr);
#pragma unroll
    for (int m = 0; m < 4; ++m)
#pragma unroll
      for (int rg = 0; rg < 4; ++rg) {
        int row = row0 + wr + m * 16 + rbase + rg;
#pragma unroll
        for (int n = 0; n < 4; ++n) {
          int col = col0 + wc + n * 16 + lr;
          float v = acc[m][n][rg];
          if (fold) v += addf[(size_t)row * N + col];
          Cp[(size_t)row * N + col] = bf16u(v);
        }
      }
  }
}

// ---------- LSTM elementwise: z = p0 + p1 (bf16 partials; z_lat pre-folded in p0) ----------
__global__ __launch_bounds__(256) void k_lstm(const unsigned short* __restrict__ zp,
                                              float* __restrict__ c_st,
                                              unsigned short* __restrict__ A1,
                                              unsigned short* __restrict__ A2,
                                              const float* __restrict__ Wmu,
                                              const float* __restrict__ bmu,
                                              float* __restrict__ out, int t) {
  __shared__ float red[4];
  const size_t Z1 = (size_t)1024 * 4096;
  int r = blockIdx.x; int tid = threadIdx.x; int j = tid * 4;
  float g4[4][4];
#pragma unroll
  for (int g = 0; g < 4; ++g) {
    const ushort4 p0 = *(const ushort4*)&zp[(size_t)r * 4096 + g * 1024 + j];
    const ushort4 p1 = *(const ushort4*)&zp[Z1 + (size_t)r * 4096 + g * 1024 + j];
    g4[g][0] = b2f(p0.x) + b2f(p1.x);
    g4[g][1] = b2f(p0.y) + b2f(p1.y);
    g4[g][2] = b2f(p0.z) + b2f(p1.z);
    g4[g][3] = b2f(p0.w) + b2f(p1.w);
  }
  const float4 cv = *(const float4*)&c_st[(size_t)r * 1024 + j];
  const float4 wm = *(const float4*)&Wmu[j];
  float cc[4] = {cv.x, cv.y, cv.z, cv.w}, wv[4] = {wm.x, wm.y, wm.z, wm.w};
  float cn[4], hn[4];
  float part = 0.f;
#pragma unroll
  for (int q = 0; q < 4; ++q) {
    float c2 = sigmoidf_(g4[1][q]) * cc[q] + sigmoidf_(g4[0][q]) * tanhf_(g4[2][q]);
    float h2 = sigmoidf_(g4[3][q]) * tanhf_(c2);
    cn[q] = c2; hn[q] = h2; part += h2 * wv[q];
  }
  *(float4*)&c_st[(size_t)r * 1024 + j] = make_float4(cn[0], cn[1], cn[2], cn[3]);
  *(ushort4*)&A2[(size_t)r * 2048 + j]        = pack4(hn[0], hn[1], hn[2], hn[3]);
  *(ushort4*)&A2[(size_t)r * 2048 + 1024 + j] = pack4(cn[0], cn[1], cn[2], cn[3]);
  *(ushort4*)&A1[(size_t)r * 2048 + 1024 + j] = pack4(hn[0], hn[1], hn[2], hn[3]);
#pragma unroll
  for (int off = 32; off > 0; off >>= 1) part += __shfl_down(part, off, 64);
  if ((tid & 63) == 0) red[tid >> 6] = part;
  __syncthreads();
  if (tid == 0) out[(size_t)r * T_ + t] = red[0] + red[1] + red[2] + red[3] + bmu[0];
}

// ---------- attention: spre = sum8 partials (s_lat pre-folded) -> tanh -> softmax -> ctx ----------
__global__ __launch_bounds__(256) void k_attn(const unsigned short* __restrict__ sp8,
                                              const float* __restrict__ latent,
                                              unsigned short* __restrict__ A1) {
  __shared__ float red[4];
  const size_t P = (size_t)1024 * 1024;
  int r = blockIdx.x; int tid = threadIdx.x; int j = tid * 4;
  float sv[4] = {0.f, 0.f, 0.f, 0.f};
#pragma unroll
  for (int sidx = 0; sidx < 8; ++sidx) {
    const ushort4 q = *(const ushort4*)&sp8[sidx * P + (size_t)r * 1024 + j];
    sv[0] += b2f(q.x); sv[1] += b2f(q.y); sv[2] += b2f(q.z); sv[3] += b2f(q.w);
  }
  float s[4] = {tanhf_(sv[0]), tanhf_(sv[1]), tanhf_(sv[2]), tanhf_(sv[3])};
  float mx = fmaxf(fmaxf(s[0], s[1]), fmaxf(s[2], s[3]));
#pragma unroll
  for (int off = 32; off > 0; off >>= 1) mx = fmaxf(mx, __shfl_xor(mx, off, 64));
  if ((tid & 63) == 0) red[tid >> 6] = mx;
  __syncthreads();
  mx = fmaxf(fmaxf(red[0], red[1]), fmaxf(red[2], red[3]));
  __syncthreads();
  float e[4], ps = 0.f;
#pragma unroll
  for (int q = 0; q < 4; ++q) { e[q] = __expf(s[q] - mx); ps += e[q]; }
#pragma unroll
  for (int off = 32; off > 0; off >>= 1) ps += __shfl_xor(ps, off, 64);
  if ((tid & 63) == 0) red[tid >> 6] = ps;
  __syncthreads();
  float inv = 1.f / (red[0] + red[1] + red[2] + red[3]);
  const float4 lv = *(const float4*)&latent[(size_t)r * 1024 + j];
  *(ushort4*)&A1[(size_t)r * 2048 + j] =
      pack4(e[0] * inv * lv.x, e[1] * inv * lv.y, e[2] * inv * lv.z, e[3] * inv * lv.w);
}

extern "C" void kernel_launch(void* const* d_in, const int* in_sizes, int n_in,
                              void* d_out, int out_size, void* d_ws, size_t ws_size,
                              hipStream_t stream) {
  const float* latent = (const float*)d_in[0];
  const float* h0  = (const float*)d_in[1];
  const float* c0  = (const float*)d_in[2];
  const float* Wk  = (const float*)d_in[3];
  const float* Wr  = (const float*)d_in[4];
  const float* b   = (const float*)d_in[5];
  const float* W1  = (const float*)d_in[6];
  const float* b1  = (const float*)d_in[7];
  const float* W2  = (const float*)d_in[8];
  const float* b2  = (const float*)d_in[9];
  const float* Wmu = (const float*)d_in[10];
  const float* bmu = (const float*)d_in[11];
  float* out = (float*)d_out;

  char* p = (char*)d_ws;
  auto alloc = [&](size_t bytes) { void* r = (void*)p; p += (bytes + 255) & ~(size_t)255; return r; };
  unsigned short* Wzh_t = (unsigned short*)alloc((size_t)4096 * 2048 * 2);  // [n][k] k<1024:Wk_bot, else Wr
  unsigned short* Wk1_t = (unsigned short*)alloc((size_t)4096 * 1024 * 2);  // Wk_top^T
  unsigned short* W1t   = (unsigned short*)alloc((size_t)1024 * 1024 * 2);
  unsigned short* W2t   = (unsigned short*)alloc((size_t)1024 * 2048 * 2);
  unsigned short* latbf = (unsigned short*)alloc((size_t)1024 * 1024 * 2);
  unsigned short* A1    = (unsigned short*)alloc((size_t)1024 * 2048 * 2);  // [ctx | h] bf16
  unsigned short* A2    = (unsigned short*)alloc((size_t)1024 * 2048 * 2);  // [h | c] bf16
  float* z_lat  = (float*)alloc((size_t)1024 * 4096 * 4);
  float* s_lat  = (float*)alloc((size_t)1024 * 1024 * 4);
  unsigned short* z_part = (unsigned short*)alloc((size_t)2 * 1024 * 4096 * 2);
  unsigned short* spre_p = (unsigned short*)alloc((size_t)8 * 1024 * 1024 * 2);
  float* c_st   = (float*)alloc((size_t)1024 * 1024 * 4);
  float* bias_s = (float*)alloc((size_t)1024 * 4);

  dim3 tb(32, 8);
  k_transpose<<<dim3(128, 32), tb, 0, stream>>>(Wk, 4096, Wk1_t, 1024, 0);
  k_transpose<<<dim3(128, 32), tb, 0, stream>>>(Wk + (size_t)1024 * 4096, 4096, Wzh_t, 2048, 0);
  k_transpose<<<dim3(128, 32), tb, 0, stream>>>(Wr, 4096, Wzh_t, 2048, 1024);
  k_transpose<<<dim3(32, 64), tb, 0, stream>>>(W2, 1024, W2t, 2048, 0);
  k_transpose<<<dim3(32, 32), tb, 0, stream>>>(W1, 1024, W1t, 1024, 0);

  k_init<<<1024, 256, 0, stream>>>(h0, c0, latent, A1, A2, latbf, c_st);
  k_bias<<<4, 256, 0, stream>>>(b1, b2, bias_s);

  // setup GEMMs (f32 + bias): z_lat = latent@Wk_top + b ; s_lat = latent@W1 + (b1+b2)
  k_gemm<<<dim3(32, 8, 1), 256, 0, stream>>>(latbf, 1024, Wk1_t, 1024, 1024, b, z_lat, nullptr, nullptr, 4096);
  k_gemm<<<dim3(8, 8, 1), 256, 0, stream>>>(latbf, 1024, W1t, 1024, 1024, bias_s, s_lat, nullptr, nullptr, 1024);

  // initial attention partials from (h0, c0); chunk0 folds s_lat
  k_gemm<<<dim3(8, 8, 8), 256, 0, stream>>>(A2, 2048, W2t, 2048, 256, nullptr, nullptr, spre_p, s_lat, 1024);
  k_attn<<<1024, 256, 0, stream>>>(spre_p, latent, A1);

  for (int t = 0; t < T_; ++t) {
    // z partials = [ctx|h]@Wzh (splitK2); chunk0 folds z_lat
    k_gemm<<<dim3(32, 8, 2), 256, 0, stream>>>(A1, 2048, Wzh_t, 2048, 1024, nullptr, nullptr, z_part, z_lat, 4096);
    k_lstm<<<1024, 256, 0, stream>>>(z_part, c_st, A1, A2, Wmu, bmu, out, t);
    if (t < T_ - 1) {
      k_gemm<<<dim3(8, 8, 8), 256, 0, stream>>>(A2, 2048, W2t, 2048, 256, nullptr, nullptr, spre_p, s_lat, 1024);
      k_attn<<<1024, 256, 0, stream>>>(spre_p, latent, A1);
    }
  }
}

// Round 8
// 1650.316 us; speedup vs baseline: 1.4197x; 1.4045x over previous
//
#include <hip/hip_runtime.h>

// Decoder: T=32-step attention LSTM, BATCH=LATENT=HIDDEN=1024.
// R8 = R3 exact structure (best: 1640us) with z_lat/s_lat stored as bf16.
//   NO epilogue folds (R6/R7 lesson: f32 fold in GEMM epilogue = latency-exposed
//   tail, +13us/dispatch). z_lat/s_lat added consumer-side (lstm/attn) where the
//   stream overlaps. GEMM core: 128x128, BK=64 dbuf (64KB LDS), T2 both-sides
//   swizzle, global_load_lds w=16, __syncthreads (counted-vmcnt was null, R7).

#define T_ 32

typedef __attribute__((ext_vector_type(8))) short short8;
typedef __attribute__((ext_vector_type(4))) float f32x4;

__device__ __forceinline__ unsigned short bf16u(float x) {
  unsigned int u = __float_as_uint(x);
  u += 0x7FFFu + ((u >> 16) & 1u);
  return (unsigned short)(u >> 16);
}
__device__ __forceinline__ float b2f(unsigned short u) {
  return __uint_as_float(((unsigned int)u) << 16);
}
__device__ __forceinline__ ushort4 pack4(float a, float b, float c, float d) {
  ushort4 v; v.x = bf16u(a); v.y = bf16u(b); v.z = bf16u(c); v.w = bf16u(d); return v;
}
__device__ __forceinline__ float sigmoidf_(float x) { return 1.f / (1.f + __expf(-x)); }
__device__ __forceinline__ float tanhf_(float x) { return 1.f - 2.f / (__expf(2.f * x) + 1.f); }

// ---------- transpose f32 [srcK][srcN] -> bf16 dst[n][dstStride] at col offset ----------
__global__ void k_transpose(const float* __restrict__ src, int srcN,
                            unsigned short* __restrict__ dst, int dstStride, int dstColOff) {
  __shared__ float tile[32][33];
  int n0 = blockIdx.x * 32, k0 = blockIdx.y * 32;
  int tx = threadIdx.x, ty = threadIdx.y;
#pragma unroll
  for (int i = 0; i < 4; ++i)
    tile[ty + i * 8][tx] = src[(size_t)(k0 + ty + i * 8) * srcN + n0 + tx];
  __syncthreads();
#pragma unroll
  for (int i = 0; i < 4; ++i)
    dst[(size_t)(n0 + ty + i * 8) * dstStride + dstColOff + k0 + tx] = bf16u(tile[tx][ty + i * 8]);
}

// ---------- one-time init ----------
__global__ __launch_bounds__(256) void k_init(const float* __restrict__ h0,
                                              const float* __restrict__ c0,
                                              const float* __restrict__ latent,
                                              unsigned short* __restrict__ A1,
                                              unsigned short* __restrict__ A2,
                                              unsigned short* __restrict__ latbf,
                                              float* __restrict__ c_st) {
  int r = blockIdx.x; int j = threadIdx.x * 4;
  const float4 hv = *(const float4*)&h0[(size_t)r * 1024 + j];
  const float4 cv = *(const float4*)&c0[(size_t)r * 1024 + j];
  const float4 lv = *(const float4*)&latent[(size_t)r * 1024 + j];
  *(ushort4*)&A2[(size_t)r * 2048 + j]        = pack4(hv.x, hv.y, hv.z, hv.w);
  *(ushort4*)&A2[(size_t)r * 2048 + 1024 + j] = pack4(cv.x, cv.y, cv.z, cv.w);
  *(ushort4*)&A1[(size_t)r * 2048 + 1024 + j] = pack4(hv.x, hv.y, hv.z, hv.w);
  *(ushort4*)&latbf[(size_t)r * 1024 + j]     = pack4(lv.x, lv.y, lv.z, lv.w);
  *(float4*)&c_st[(size_t)r * 1024 + j] = cv;
}

__global__ void k_bias(const float* __restrict__ b1, const float* __restrict__ b2,
                       float* __restrict__ bias_s) {
  int i = blockIdx.x * 256 + threadIdx.x;
  bias_s[i] = b1[i] + b2[i];
}

// ---------- MFMA GEMM (split-K, 2-phase dbuf BK=64, T2 both-sides swizzle) ----------
// Output: bf16 at Cb[blockIdx.z][1024][N]. If bias!=null (setup GEMMs,
// gridDim.z==1): adds bias[col] before rounding.
__global__ __launch_bounds__(256) void k_gemm(const unsigned short* __restrict__ A, int lda,
                                              const unsigned short* __restrict__ Bt, int ldb,
                                              int Kchunk,
                                              const float* __restrict__ bias,
                                              unsigned short* __restrict__ Cb, int N) {
  __shared__ unsigned short Al[2][128 * 64];
  __shared__ unsigned short Bl[2][128 * 64];
  const int tid = threadIdx.x;
  const int w = tid >> 6, l = tid & 63;
  const int row0 = blockIdx.y * 128, col0 = blockIdx.x * 128;
  const int wr = (w >> 1) * 64, wc = (w & 1) * 64;
  const int lr = l & 15;
  const int srow = (l >> 3);                       // 0..7 within chunk
  const int scol_src = ((l & 7) ^ srow) * 8;       // swizzled global column (elements)
  const int kbeg = blockIdx.z * Kchunk;
  const int nsteps = Kchunk >> 6;

  f32x4 acc[4][4] = {};

  auto stage = [&](int buf, int k0) {
#pragma unroll
    for (int it = 0; it < 4; ++it) {
      int chunk = w * 4 + it;           // wave-uniform
      int r = chunk * 8 + srow;
      const unsigned short* ga = A + (size_t)(row0 + r) * lda + k0 + scol_src;
      const unsigned short* gb = Bt + (size_t)(col0 + r) * ldb + k0 + scol_src;
      __builtin_amdgcn_global_load_lds(
          (const __attribute__((address_space(1))) unsigned int*)ga,
          (__attribute__((address_space(3))) unsigned int*)((char*)&Al[buf][0] + chunk * 1024), 16, 0, 0);
      __builtin_amdgcn_global_load_lds(
          (const __attribute__((address_space(1))) unsigned int*)gb,
          (__attribute__((address_space(3))) unsigned int*)((char*)&Bl[buf][0] + chunk * 1024), 16, 0, 0);
    }
  };

  stage(0, kbeg);
  __syncthreads();
  int cur = 0;
  for (int s = 0; s < nsteps; ++s) {
    if (s + 1 < nsteps) stage(cur ^ 1, kbeg + (s + 1) * 64);  // prefetch next tile
#pragma unroll
    for (int kk = 0; kk < 2; ++kk) {
      const int c2 = kk * 64 + (l >> 4) * 16;     // byte col within 128B row
      short8 a[4], b[4];
#pragma unroll
      for (int m = 0; m < 4; ++m) {
        int r = wr + m * 16 + lr;
        a[m] = *(const short8*)((char*)&Al[cur][0] + r * 128 + (c2 ^ ((r & 7) << 4)));
      }
#pragma unroll
      for (int n = 0; n < 4; ++n) {
        int r = wc + n * 16 + lr;
        b[n] = *(const short8*)((char*)&Bl[cur][0] + r * 128 + (c2 ^ ((r & 7) << 4)));
      }
#pragma unroll
      for (int m = 0; m < 4; ++m)
#pragma unroll
        for (int n = 0; n < 4; ++n)
          acc[m][n] = __builtin_amdgcn_mfma_f32_16x16x32_bf16(a[m], b[n], acc[m][n], 0, 0, 0);
    }
    __syncthreads();
    cur ^= 1;
  }

  const int rbase = (l >> 4) * 4;
  unsigned short* Cp = Cb + (size_t)blockIdx.z * (size_t)(gridDim.y * 128) * N;
#pragma unroll
  for (int m = 0; m < 4; ++m)
#pragma unroll
    for (int rg = 0; rg < 4; ++rg) {
      int row = row0 + wr + m * 16 + rbase + rg;
#pragma unroll
      for (int n = 0; n < 4; ++n) {
        int col = col0 + wc + n * 16 + lr;
        float v = acc[m][n][rg];
        if (bias) v += bias[col];
        Cp[(size_t)row * N + col] = bf16u(v);
      }
    }
}

// ---------- LSTM elementwise: z = z_latb + p0 + p1 (all bf16) ----------
__global__ __launch_bounds__(256) void k_lstm(const unsigned short* __restrict__ z_latb,
                                              const unsigned short* __restrict__ zp,
                                              float* __restrict__ c_st,
                                              unsigned short* __restrict__ A1,
                                              unsigned short* __restrict__ A2,
                                              const float* __restrict__ Wmu,
                                              const float* __restrict__ bmu,
                                              float* __restrict__ out, int t) {
  __shared__ float red[4];
  const size_t Z1 = (size_t)1024 * 4096;
  int r = blockIdx.x; int tid = threadIdx.x; int j = tid * 4;
  float g4[4][4];
#pragma unroll
  for (int g = 0; g < 4; ++g) {
    const ushort4 zl = *(const ushort4*)&z_latb[(size_t)r * 4096 + g * 1024 + j];
    const ushort4 p0 = *(const ushort4*)&zp[(size_t)r * 4096 + g * 1024 + j];
    const ushort4 p1 = *(const ushort4*)&zp[Z1 + (size_t)r * 4096 + g * 1024 + j];
    g4[g][0] = b2f(zl.x) + b2f(p0.x) + b2f(p1.x);
    g4[g][1] = b2f(zl.y) + b2f(p0.y) + b2f(p1.y);
    g4[g][2] = b2f(zl.z) + b2f(p0.z) + b2f(p1.z);
    g4[g][3] = b2f(zl.w) + b2f(p0.w) + b2f(p1.w);
  }
  const float4 cv = *(const float4*)&c_st[(size_t)r * 1024 + j];
  const float4 wm = *(const float4*)&Wmu[j];
  float cc[4] = {cv.x, cv.y, cv.z, cv.w}, wv[4] = {wm.x, wm.y, wm.z, wm.w};
  float cn[4], hn[4];
  float part = 0.f;
#pragma unroll
  for (int q = 0; q < 4; ++q) {
    float c2 = sigmoidf_(g4[1][q]) * cc[q] + sigmoidf_(g4[0][q]) * tanhf_(g4[2][q]);
    float h2 = sigmoidf_(g4[3][q]) * tanhf_(c2);
    cn[q] = c2; hn[q] = h2; part += h2 * wv[q];
  }
  *(float4*)&c_st[(size_t)r * 1024 + j] = make_float4(cn[0], cn[1], cn[2], cn[3]);
  *(ushort4*)&A2[(size_t)r * 2048 + j]        = pack4(hn[0], hn[1], hn[2], hn[3]);
  *(ushort4*)&A2[(size_t)r * 2048 + 1024 + j] = pack4(cn[0], cn[1], cn[2], cn[3]);
  *(ushort4*)&A1[(size_t)r * 2048 + 1024 + j] = pack4(hn[0], hn[1], hn[2], hn[3]);
#pragma unroll
  for (int off = 32; off > 0; off >>= 1) part += __shfl_down(part, off, 64);
  if ((tid & 63) == 0) red[tid >> 6] = part;
  __syncthreads();
  if (tid == 0) out[(size_t)r * T_ + t] = red[0] + red[1] + red[2] + red[3] + bmu[0];
}

// ---------- attention: spre = s_latb + sum8 partials -> tanh -> softmax -> ctx ----------
__global__ __launch_bounds__(256) void k_attn(const unsigned short* __restrict__ s_latb,
                                              const unsigned short* __restrict__ sp8,
                                              const float* __restrict__ latent,
                                              unsigned short* __restrict__ A1) {
  __shared__ float red[4];
  const size_t P = (size_t)1024 * 1024;
  int r = blockIdx.x; int tid = threadIdx.x; int j = tid * 4;
  const ushort4 sl = *(const ushort4*)&s_latb[(size_t)r * 1024 + j];
  float sv[4] = {b2f(sl.x), b2f(sl.y), b2f(sl.z), b2f(sl.w)};
#pragma unroll
  for (int sidx = 0; sidx < 8; ++sidx) {
    const ushort4 q = *(const ushort4*)&sp8[sidx * P + (size_t)r * 1024 + j];
    sv[0] += b2f(q.x); sv[1] += b2f(q.y); sv[2] += b2f(q.z); sv[3] += b2f(q.w);
  }
  float s[4] = {tanhf_(sv[0]), tanhf_(sv[1]), tanhf_(sv[2]), tanhf_(sv[3])};
  float mx = fmaxf(fmaxf(s[0], s[1]), fmaxf(s[2], s[3]));
#pragma unroll
  for (int off = 32; off > 0; off >>= 1) mx = fmaxf(mx, __shfl_xor(mx, off, 64));
  if ((tid & 63) == 0) red[tid >> 6] = mx;
  __syncthreads();
  mx = fmaxf(fmaxf(red[0], red[1]), fmaxf(red[2], red[3]));
  __syncthreads();
  float e[4], ps = 0.f;
#pragma unroll
  for (int q = 0; q < 4; ++q) { e[q] = __expf(s[q] - mx); ps += e[q]; }
#pragma unroll
  for (int off = 32; off > 0; off >>= 1) ps += __shfl_xor(ps, off, 64);
  if ((tid & 63) == 0) red[tid >> 6] = ps;
  __syncthreads();
  float inv = 1.f / (red[0] + red[1] + red[2] + red[3]);
  const float4 lv = *(const float4*)&latent[(size_t)r * 1024 + j];
  *(ushort4*)&A1[(size_t)r * 2048 + j] =
      pack4(e[0] * inv * lv.x, e[1] * inv * lv.y, e[2] * inv * lv.z, e[3] * inv * lv.w);
}

extern "C" void kernel_launch(void* const* d_in, const int* in_sizes, int n_in,
                              void* d_out, int out_size, void* d_ws, size_t ws_size,
                              hipStream_t stream) {
  const float* latent = (const float*)d_in[0];
  const float* h0  = (const float*)d_in[1];
  const float* c0  = (const float*)d_in[2];
  const float* Wk  = (const float*)d_in[3];
  const float* Wr  = (const float*)d_in[4];
  const float* b   = (const float*)d_in[5];
  const float* W1  = (const float*)d_in[6];
  const float* b1  = (const float*)d_in[7];
  const float* W2  = (const float*)d_in[8];
  const float* b2  = (const float*)d_in[9];
  const float* Wmu = (const float*)d_in[10];
  const float* bmu = (const float*)d_in[11];
  float* out = (float*)d_out;

  char* p = (char*)d_ws;
  auto alloc = [&](size_t bytes) { void* r = (void*)p; p += (bytes + 255) & ~(size_t)255; return r; };
  unsigned short* Wzh_t = (unsigned short*)alloc((size_t)4096 * 2048 * 2);  // [n][k] k<1024:Wk_bot, else Wr
  unsigned short* Wk1_t = (unsigned short*)alloc((size_t)4096 * 1024 * 2);  // Wk_top^T
  unsigned short* W1t   = (unsigned short*)alloc((size_t)1024 * 1024 * 2);
  unsigned short* W2t   = (unsigned short*)alloc((size_t)1024 * 2048 * 2);
  unsigned short* latbf = (unsigned short*)alloc((size_t)1024 * 1024 * 2);
  unsigned short* A1    = (unsigned short*)alloc((size_t)1024 * 2048 * 2);  // [ctx | h] bf16
  unsigned short* A2    = (unsigned short*)alloc((size_t)1024 * 2048 * 2);  // [h | c] bf16
  unsigned short* z_latb = (unsigned short*)alloc((size_t)1024 * 4096 * 2); // bf16
  unsigned short* s_latb = (unsigned short*)alloc((size_t)1024 * 1024 * 2); // bf16
  unsigned short* z_part = (unsigned short*)alloc((size_t)2 * 1024 * 4096 * 2);
  unsigned short* spre_p = (unsigned short*)alloc((size_t)8 * 1024 * 1024 * 2);
  float* c_st   = (float*)alloc((size_t)1024 * 1024 * 4);
  float* bias_s = (float*)alloc((size_t)1024 * 4);

  dim3 tb(32, 8);
  k_transpose<<<dim3(128, 32), tb, 0, stream>>>(Wk, 4096, Wk1_t, 1024, 0);
  k_transpose<<<dim3(128, 32), tb, 0, stream>>>(Wk + (size_t)1024 * 4096, 4096, Wzh_t, 2048, 0);
  k_transpose<<<dim3(128, 32), tb, 0, stream>>>(Wr, 4096, Wzh_t, 2048, 1024);
  k_transpose<<<dim3(32, 64), tb, 0, stream>>>(W2, 1024, W2t, 2048, 0);
  k_transpose<<<dim3(32, 32), tb, 0, stream>>>(W1, 1024, W1t, 1024, 0);

  k_init<<<1024, 256, 0, stream>>>(h0, c0, latent, A1, A2, latbf, c_st);
  k_bias<<<4, 256, 0, stream>>>(b1, b2, bias_s);

  // setup GEMMs (bf16 out + bias): z_latb = latent@Wk_top + b ; s_latb = latent@W1 + (b1+b2)
  k_gemm<<<dim3(32, 8, 1), 256, 0, stream>>>(latbf, 1024, Wk1_t, 1024, 1024, b, z_latb, 4096);
  k_gemm<<<dim3(8, 8, 1), 256, 0, stream>>>(latbf, 1024, W1t, 1024, 1024, bias_s, s_latb, 1024);

  // initial attention partials from (h0, c0)
  k_gemm<<<dim3(8, 8, 8), 256, 0, stream>>>(A2, 2048, W2t, 2048, 256, nullptr, spre_p, 1024);
  k_attn<<<1024, 256, 0, stream>>>(s_latb, spre_p, latent, A1);

  for (int t = 0; t < T_; ++t) {
    // z partials = [ctx|h]@Wzh (splitK2)
    k_gemm<<<dim3(32, 8, 2), 256, 0, stream>>>(A1, 2048, Wzh_t, 2048, 1024, nullptr, z_part, 4096);
    k_lstm<<<1024, 256, 0, stream>>>(z_latb, z_part, c_st, A1, A2, Wmu, bmu, out, t);
    if (t < T_ - 1) {
      k_gemm<<<dim3(8, 8, 8), 256, 0, stream>>>(A2, 2048, W2t, 2048, 256, nullptr, spre_p, 1024);
      k_attn<<<1024, 256, 0, stream>>>(s_latb, spre_p, latent, A1);
    }
  }
}